// Round 4
// baseline (414.428 us; speedup 1.0000x reference)
//
#include <hip/hip_runtime.h>
#include <stdint.h>

// GeometricPositionalFingerprinter on MI355X — round 4: no-LDS, no-barrier.
//
// One anchor per 4-lane group, ONE iteration per thread (grid covers all
// anchors). Lane r in 0..3 loads float4s r, 4+r, 8+r, 12+r of each vertex:
// per (v,k) load instruction the 4 lanes of an anchor cover exactly one 64B
// line (16 anchors/wave -> 1KB/instr, 100% used). All 20 loads are
// independent and issue before the single vmcnt wait.
// The 15 Gram inner products ip[v][w] accumulate in f64 (products of f32 are
// exact in f64); 2-step shfl_xor butterfly over the 4-lane group; then all 4
// lanes redundantly run the scalar tail from registers (no LDS handoff, no
// __syncthreads -> waves retire independently, occupancy bound by VGPRs only):
//   dist^2(i,j)   = ip_ii + ip_jj - 2 ip_ij            (edges only)
//   |v_i - c|^2   = ip_ii - 2/5 rowsum_i + totsum/25    (spread)
//   V^2           = det(G)/576, G[i][j] = ip00 - ip0i - ip0j + ipij
//   (closed-form 4x4 cofactor det == -det(CM)/9216 of the reference)
// All sensitive math in f64: Cantor digits amplify seed error by 3^k; this
// pipeline matches the np reference to the last digit (absmax 2^-8, R1-R3).

#define THREADS 256

__global__ __launch_bounds__(THREADS, 4) void fingerprint_kernel(
    const float* __restrict__ vertices,
    const void* __restrict__ ids_raw,
    float* __restrict__ out,
    int n)
{
    const int tid  = threadIdx.x;
    const int r    = tid & 3;                       // dim-chunk lane
    const int a    = blockIdx.x * (THREADS / 4) + (tid >> 2);
    const int aload = (a < n) ? a : (n - 1);
    const float* vb = vertices + (size_t)aload * 320;

    // ---------------- loads: 20 independent float4s ----------------
    float xv[5][4][4];                              // [vertex][k][component]
    #pragma unroll
    for (int v = 0; v < 5; ++v)
        #pragma unroll
        for (int k = 0; k < 4; ++k) {
            float4 t = *(const float4*)(vb + v * 64 + k * 16 + r * 4);
            xv[v][k][0] = t.x; xv[v][k][1] = t.y;
            xv[v][k][2] = t.z; xv[v][k][3] = t.w;
        }

    // ---------------- 15 Gram inner products ----------------
    double ip[15];
    #pragma unroll
    for (int p = 0; p < 15; ++p) ip[p] = 0.0;

    #pragma unroll
    for (int k = 0; k < 4; ++k)
        #pragma unroll
        for (int c = 0; c < 4; ++c) {
            double x[5];
            #pragma unroll
            for (int v = 0; v < 5; ++v) x[v] = (double)xv[v][k][c];
            int p = 0;
            #pragma unroll
            for (int v = 0; v < 5; ++v)
                #pragma unroll
                for (int w = v; w < 5; ++w) {
                    ip[p] = fma(x[v], x[w], ip[p]);
                    ++p;
                }
        }

    // 2-step butterfly over the 4-lane group: all 4 lanes get all 15 sums
    #pragma unroll
    for (int p = 0; p < 15; ++p) {
        ip[p] += __shfl_xor(ip[p], 1);
        ip[p] += __shfl_xor(ip[p], 2);
    }

    // ---------------- scalar tail (redundant on the 4 lanes) ----------------
    // ip index lookup: linear upper-triangular order
    const int IP[5][5] = {
        { 0, 1, 2, 3, 4},
        { 1, 5, 6, 7, 8},
        { 2, 6, 9,10,11},
        { 3, 7,10,12,13},
        { 4, 8,11,13,14}};

    // edge stats over 10 unique edges (unbiased std)
    double e[10], esum = 0.0;
    {
        int p = 0;
        #pragma unroll
        for (int i = 0; i < 5; ++i)
            #pragma unroll
            for (int j = i + 1; j < 5; ++j) {
                double d = ip[IP[i][i]] + ip[IP[j][j]] - 2.0 * ip[IP[i][j]];
                e[p] = sqrt(d); esum += e[p]; ++p;
            }
    }
    double emean = esum * 0.1;
    double evar = 0.0;
    #pragma unroll
    for (int p = 0; p < 10; ++p) { double d = e[p] - emean; evar += d * d; }
    double estd = sqrt(evar / 9.0);

    // spread: std of distances to centroid (unbiased)
    double rowsum[5], tot = 0.0;
    #pragma unroll
    for (int i = 0; i < 5; ++i) {
        double s = 0.0;
        #pragma unroll
        for (int w = 0; w < 5; ++w) s += ip[IP[i][w]];
        rowsum[i] = s; tot += s;
    }
    double c2 = tot * 0.04;                         // |centroid|^2 = tot/25
    double dsum = 0.0, dd[5];
    #pragma unroll
    for (int i = 0; i < 5; ++i) {
        double s2 = ip[IP[i][i]] - 0.4 * rowsum[i] + c2;   // |v_i - c|^2
        dd[i] = sqrt(fmax(s2, 0.0)); dsum += dd[i];
    }
    double dmean = dsum * 0.2;
    double svar = 0.0;
    #pragma unroll
    for (int i = 0; i < 5; ++i) { double d = dd[i] - dmean; svar += d * d; }
    double spread = sqrt(svar * 0.25);

    // 4-simplex volume: G[i][j] = <v_i - v_0, v_j - v_0> directly from ips
    double G[4][4];
    #pragma unroll
    for (int i = 0; i < 4; ++i)
        #pragma unroll
        for (int j = 0; j < 4; ++j)
            G[i][j] = ip[IP[0][0]] - ip[IP[0][i + 1]] - ip[IP[0][j + 1]]
                    + ip[IP[i + 1][j + 1]];

    double m01 = G[2][2] * G[3][3] - G[2][3] * G[3][2];
    double m02 = G[2][1] * G[3][3] - G[2][3] * G[3][1];
    double m03 = G[2][1] * G[3][2] - G[2][2] * G[3][1];
    double m04 = G[2][0] * G[3][3] - G[2][3] * G[3][0];
    double m05 = G[2][0] * G[3][2] - G[2][2] * G[3][0];
    double m06 = G[2][0] * G[3][1] - G[2][1] * G[3][0];
    double det =
        G[0][0] * (G[1][1] * m01 - G[1][2] * m02 + G[1][3] * m03)
      - G[0][1] * (G[1][0] * m01 - G[1][2] * m04 + G[1][3] * m05)
      + G[0][2] * (G[1][0] * m02 - G[1][1] * m04 + G[1][3] * m06)
      - G[0][3] * (G[1][0] * m03 - G[1][1] * m05 + G[1][2] * m06);

    double volume = sqrt(fmax(det / 576.0, 0.0));

    double vn = 1.0 / (1.0 + exp(-10.0 * volume));
    double er = 1.0 / (1.0 + exp(-(estd / (emean + 1e-6))));
    double sn = 1.0 / (1.0 + exp(-spread));
    double seed = 0.4 * vn + 0.3 * er + 0.3 * sn;

    // anchor id hash: probe whether ids are int64 (jax x64) or int32 layout
    const int* ai32 = (const int*)ids_raw;
    long long idv;
    if (ai32[1] == 0) {           // int64 little-endian: high word of id0
        idv = ((const long long*)ids_raw)[aload];
    } else {
        idv = (long long)ai32[aload];
    }
    long long h = (idv * 2654435761LL) % 1000000LL;
    double idc = (double)h / 1000000.0;

    seed = 0.1 * seed + 0.9 * idc;
    seed = fmin(fmax(seed, 1e-6), 1.0 - 1e-6);

    // Cantor digit extraction
    double x = seed, cant = 0.0, factor = 0.5;
    #pragma unroll
    for (int itc = 0; itc < 8; ++itc) {
        double xs = x * 3.0;
        int dg = (int)xs;           // trunc, xs in [0,3)
        x = xs - (double)dg;
        cant += (dg == 2) ? factor : 0.0;
        factor *= 0.5;
    }

    if (r == 0 && a < n)
        out[a] = (float)fmin(fmax(cant, 0.0), 1.0);
}

extern "C" void kernel_launch(void* const* d_in, const int* in_sizes, int n_in,
                              void* d_out, int out_size, void* d_ws, size_t ws_size,
                              hipStream_t stream) {
    const float* vertices = (const float*)d_in[0];
    const void*  ids      = d_in[1];
    float* out = (float*)d_out;
    int n = in_sizes[1];            // anchor count (element count of anchor_ids)
    int anchorsPerBlock = THREADS / 4;
    int grid = (n + anchorsPerBlock - 1) / anchorsPerBlock;
    fingerprint_kernel<<<grid, THREADS, 0, stream>>>(vertices, ids, out, n);
}

// Round 5
// 340.698 us; speedup vs baseline: 1.2164x; 1.2164x over previous
//
#include <hip/hip_runtime.h>
#include <stdint.h>

// GeometricPositionalFingerprinter on MI355X — round 5: R4 structure, spill fix.
//
// R4's __launch_bounds__(256,4) capped the allocator at 64 VGPRs while the
// kernel holds ~110 live -> 322 MB/launch of scratch spills (rocprof R4:
// WRITE_SIZE 322 MB vs 0.8 MB ideal). Fix: (256,2) -> 128-VGPR cap, and stage
// loads per k-slice (5 float4 = 20 VGPRs) instead of all 20 float4s (80),
// so peak pressure ~= ip(30 VGPRs f64) + ~2 pipelined slices + addressing.
//
// One anchor per 4-lane group, one iteration per thread. Lane r loads float4
// k*4+r of each vertex: per (v,k) instruction the anchor's 4 lanes cover one
// 64B line (16 anchors/wave -> 1KB/instr, 100% used). No LDS, no barrier —
// waves retire independently. 15 Gram inner products in f64 (exact for f32
// products); 2-step shfl_xor butterfly; all 4 lanes redundantly run the
// scalar tail; lane 0 stores.
//   dist^2(i,j) = ip_ii + ip_jj - 2 ip_ij
//   |v_i - c|^2 = ip_ii - 2/5 rowsum_i + totsum/25
//   V^2 = det(G)/576, G[i][j] = ip00 - ip0i - ip0j + ipij  (== -det(CM)/9216)
// All sensitive math in f64: Cantor digits amplify seed error 3^k; this
// pipeline matches the np reference to the last digit (absmax 2^-8, R1-R4).

#define THREADS 256

__global__ __launch_bounds__(THREADS, 2) void fingerprint_kernel(
    const float* __restrict__ vertices,
    const void* __restrict__ ids_raw,
    float* __restrict__ out,
    int n)
{
    const int tid  = threadIdx.x;
    const int r    = tid & 3;                       // dim-chunk lane
    const int a    = blockIdx.x * (THREADS / 4) + (tid >> 2);
    const int aload = (a < n) ? a : (n - 1);
    const float* vb = vertices + (size_t)aload * 320 + r * 4;

    // ---------------- 15 Gram inner products, staged per k-slice ----------
    double ip[15];
    #pragma unroll
    for (int p = 0; p < 15; ++p) ip[p] = 0.0;

    #pragma unroll
    for (int k = 0; k < 4; ++k) {
        // 5 independent float4 loads for this k-slice (20 VGPRs live)
        float4 t0 = *(const float4*)(vb +   0 + k * 16);
        float4 t1 = *(const float4*)(vb +  64 + k * 16);
        float4 t2 = *(const float4*)(vb + 128 + k * 16);
        float4 t3 = *(const float4*)(vb + 192 + k * 16);
        float4 t4 = *(const float4*)(vb + 256 + k * 16);
        float xc[5][4] = {
            {t0.x, t0.y, t0.z, t0.w},
            {t1.x, t1.y, t1.z, t1.w},
            {t2.x, t2.y, t2.z, t2.w},
            {t3.x, t3.y, t3.z, t3.w},
            {t4.x, t4.y, t4.z, t4.w}};
        #pragma unroll
        for (int c = 0; c < 4; ++c) {
            double x[5];
            #pragma unroll
            for (int v = 0; v < 5; ++v) x[v] = (double)xc[v][c];
            int p = 0;
            #pragma unroll
            for (int v = 0; v < 5; ++v)
                #pragma unroll
                for (int w = v; w < 5; ++w) {
                    ip[p] = fma(x[v], x[w], ip[p]);
                    ++p;
                }
        }
    }

    // 2-step butterfly over the 4-lane group: all 4 lanes get all 15 sums
    #pragma unroll
    for (int p = 0; p < 15; ++p) {
        ip[p] += __shfl_xor(ip[p], 1);
        ip[p] += __shfl_xor(ip[p], 2);
    }

    // ---------------- scalar tail (redundant on the 4 lanes) ----------------
    const int IP[5][5] = {
        { 0, 1, 2, 3, 4},
        { 1, 5, 6, 7, 8},
        { 2, 6, 9,10,11},
        { 3, 7,10,12,13},
        { 4, 8,11,13,14}};

    // edge stats over 10 unique edges (unbiased std)
    double e[10], esum = 0.0;
    {
        int p = 0;
        #pragma unroll
        for (int i = 0; i < 5; ++i)
            #pragma unroll
            for (int j = i + 1; j < 5; ++j) {
                double d = ip[IP[i][i]] + ip[IP[j][j]] - 2.0 * ip[IP[i][j]];
                e[p] = sqrt(d); esum += e[p]; ++p;
            }
    }
    double emean = esum * 0.1;
    double evar = 0.0;
    #pragma unroll
    for (int p = 0; p < 10; ++p) { double d = e[p] - emean; evar += d * d; }
    double estd = sqrt(evar / 9.0);

    // spread: std of distances to centroid (unbiased)
    double rowsum[5], tot = 0.0;
    #pragma unroll
    for (int i = 0; i < 5; ++i) {
        double s = 0.0;
        #pragma unroll
        for (int w = 0; w < 5; ++w) s += ip[IP[i][w]];
        rowsum[i] = s; tot += s;
    }
    double c2 = tot * 0.04;                         // |centroid|^2 = tot/25
    double dsum = 0.0, dd[5];
    #pragma unroll
    for (int i = 0; i < 5; ++i) {
        double s2 = ip[IP[i][i]] - 0.4 * rowsum[i] + c2;   // |v_i - c|^2
        dd[i] = sqrt(fmax(s2, 0.0)); dsum += dd[i];
    }
    double dmean = dsum * 0.2;
    double svar = 0.0;
    #pragma unroll
    for (int i = 0; i < 5; ++i) { double d = dd[i] - dmean; svar += d * d; }
    double spread = sqrt(svar * 0.25);

    // 4-simplex volume: G[i][j] = <v_i - v_0, v_j - v_0> directly from ips
    double G[4][4];
    #pragma unroll
    for (int i = 0; i < 4; ++i)
        #pragma unroll
        for (int j = 0; j < 4; ++j)
            G[i][j] = ip[IP[0][0]] - ip[IP[0][i + 1]] - ip[IP[0][j + 1]]
                    + ip[IP[i + 1][j + 1]];

    double m01 = G[2][2] * G[3][3] - G[2][3] * G[3][2];
    double m02 = G[2][1] * G[3][3] - G[2][3] * G[3][1];
    double m03 = G[2][1] * G[3][2] - G[2][2] * G[3][1];
    double m04 = G[2][0] * G[3][3] - G[2][3] * G[3][0];
    double m05 = G[2][0] * G[3][2] - G[2][2] * G[3][0];
    double m06 = G[2][0] * G[3][1] - G[2][1] * G[3][0];
    double det =
        G[0][0] * (G[1][1] * m01 - G[1][2] * m02 + G[1][3] * m03)
      - G[0][1] * (G[1][0] * m01 - G[1][2] * m04 + G[1][3] * m05)
      + G[0][2] * (G[1][0] * m02 - G[1][1] * m04 + G[1][3] * m06)
      - G[0][3] * (G[1][0] * m03 - G[1][1] * m05 + G[1][2] * m06);

    double volume = sqrt(fmax(det / 576.0, 0.0));

    double vn = 1.0 / (1.0 + exp(-10.0 * volume));
    double er = 1.0 / (1.0 + exp(-(estd / (emean + 1e-6))));
    double sn = 1.0 / (1.0 + exp(-spread));
    double seed = 0.4 * vn + 0.3 * er + 0.3 * sn;

    // anchor id hash: probe whether ids are int64 (jax x64) or int32 layout
    const int* ai32 = (const int*)ids_raw;
    long long idv;
    if (ai32[1] == 0) {           // int64 little-endian: high word of id0
        idv = ((const long long*)ids_raw)[aload];
    } else {
        idv = (long long)ai32[aload];
    }
    long long h = (idv * 2654435761LL) % 1000000LL;
    double idc = (double)h / 1000000.0;

    seed = 0.1 * seed + 0.9 * idc;
    seed = fmin(fmax(seed, 1e-6), 1.0 - 1e-6);

    // Cantor digit extraction
    double x = seed, cant = 0.0, factor = 0.5;
    #pragma unroll
    for (int itc = 0; itc < 8; ++itc) {
        double xs = x * 3.0;
        int dg = (int)xs;           // trunc, xs in [0,3)
        x = xs - (double)dg;
        cant += (dg == 2) ? factor : 0.0;
        factor *= 0.5;
    }

    if (r == 0 && a < n)
        out[a] = (float)fmin(fmax(cant, 0.0), 1.0);
}

extern "C" void kernel_launch(void* const* d_in, const int* in_sizes, int n_in,
                              void* d_out, int out_size, void* d_ws, size_t ws_size,
                              hipStream_t stream) {
    const float* vertices = (const float*)d_in[0];
    const void*  ids      = d_in[1];
    float* out = (float*)d_out;
    int n = in_sizes[1];            // anchor count (element count of anchor_ids)
    int anchorsPerBlock = THREADS / 4;
    int grid = (n + anchorsPerBlock - 1) / anchorsPerBlock;
    fingerprint_kernel<<<grid, THREADS, 0, stream>>>(vertices, ids, out, n);
}